// Round 8
// baseline (194.304 us; speedup 1.0000x reference)
//
#include <hip/hip_runtime.h>
#include <cstdint>

#define GH 10
#define GW 10

// Round 13: r2 (no-LDS direct loads, best measured: harness 164.4) with the
// load path widened. r7-pipeline post-mortem: 2048 waves total = 2/SIMD,
// occupancy 10% -> latency chains exposed; LDS double-buffering halves
// resident waves (bad trade). r2's tax: 25 float2 loads/lane at 200B
// stride = 25 latency batches, ~1600 line-touches/wave. Fix: 13 loads
// (1 float2 + 12 float4), exactly aligned: h=0 = 12xf4 @record base
// (400B-aligned) + f2 @+192; h=1 = f2 @+200 + 12xf4 @+208 (16B-aligned).
// Halves load batches and line-touches; h-divergence costs only masked
// issue slots. Values and ALL arithmetic bit-identical to r2 (absmax 0).
__global__ __launch_bounds__(256, 4) void custom_loss_kernel(
    const float* __restrict__ result,
    const int* __restrict__ points,
    float* __restrict__ out,
    int B)
{
    __shared__ float wsum[4];
    const int tix = threadIdx.x;
    const int lane = tix & 63;
    const int wid = tix >> 6;

    const int s_local = tix >> 1;             // sample within block (0..127)
    const int h = tix & 1;                    // half: rows 5h..5h+4
    const int s = blockIdx.x * 128 + s_local;

    float loss = 0.f;
    if (s < B) {
        const int4 p = ((const int4*)points)[s];
        const int p0y = p.x, p0x = p.y, p1y = p.z, p1x = p.w;
        const int dy0 = abs(p0y - p1y), dx0 = abs(p0x - p1x);
        const int base0 = dy0 + dx0;
        const int idx0 = p0y * GW + p0x;
        const int idx1 = p1y * GW + p1x;

        // ---- own 5 rows (50 floats) straight from global into registers ----
        // widened: 1 float2 + 12 float4 (13 loads vs 25), both halves aligned
        const float* __restrict__ sp = result + (size_t)s * 100;
        float vv[50];
        if (h == 0) {
            const float4* __restrict__ q = (const float4*)sp;   // 400B-aligned
#pragma unroll
            for (int k = 0; k < 12; ++k) {
                const float4 t4 = q[k];
                vv[4 * k]     = t4.x; vv[4 * k + 1] = t4.y;
                vv[4 * k + 2] = t4.z; vv[4 * k + 3] = t4.w;
            }
            const float2 t2 = *(const float2*)(sp + 48);
            vv[48] = t2.x; vv[49] = t2.y;
        } else {
            const float2 t2 = *(const float2*)(sp + 50);        // +200B: 8B ok
            vv[0] = t2.x; vv[1] = t2.y;
            const float4* __restrict__ q = (const float4*)(sp + 52); // +208B
#pragma unroll
            for (int k = 0; k < 12; ++k) {
                const float4 t4 = q[k];
                vv[4 * k + 2] = t4.x; vv[4 * k + 3] = t4.y;
                vv[4 * k + 4] = t4.z; vv[4 * k + 5] = t4.w;
            }
        }
        const float rs = sp[idx0];            // L1-hot: lines just fetched
        const float re = sp[idx1];

        float adxf[10], inboxf[10];           // compile-time indexed -> regs
#pragma unroll
        for (int x = 0; x < 10; ++x) {
            const int a = abs(x - p0x) + abs(x - p1x) - dx0;
            adxf[x] = (float)a;
            inboxf[x] = (a == 0) ? 1.f : 0.f;
        }

        // ---- pass 1 over own rows ----
        float sum_h = 0.f, sc_h = 0.f, box_h = 0.f;
        uint64_t mword = 0;                   // own 50-bit mask, bit = i*10+x
#pragma unroll
        for (int i = 0; i < 5; ++i) {
            const int y = 5 * h + i;
            const float* v = vv + 10 * i;
            const float rowacc = ((v[0]+v[1])+(v[2]+v[3])) +
                                 ((v[4]+v[5])+(v[6]+v[7])) + (v[8]+v[9]);
            sum_h += rowacc;
            const int ay = abs(y - p0y) + abs(y - p1y) - dy0;
            sc_h = fmaf((float)ay, rowacc, sc_h);
            float boxrow = 0.f;
            uint32_t rm = 0u;
#pragma unroll
            for (int x = 0; x < 10; ++x) {
                sc_h = fmaf(adxf[x], v[x], sc_h);
                boxrow = fmaf(inboxf[x], v[x], boxrow);
                // jnp.round half-to-even: for v in [0,1), round==1 <=> v>0.5
                rm |= (v[x] > 0.5f) ? (1u << x) : 0u;
            }
            box_h += (ay == 0) ? boxrow : 0.f;
            mword |= (uint64_t)rm << (10 * i);
        }
        const float sum_all = sum_h + __shfl_xor(sum_h, 1);
        const float sc      = sc_h  + __shfl_xor(sc_h, 1);
        const float boxSum  = box_h + __shfl_xor(box_h, 1);
        const uint64_t mo = (uint64_t)__shfl_xor((unsigned long long)mword, 1);
        const uint64_t mlo = h ? mo : mword;
        const uint64_t mhi = h ? mword : mo;

        // ---- flood fill: full board per lane (no per-iter pair sync) ----
        const uint64_t M50 = (1ull << 50) - 1;
        const uint64_t C0  = 0x10040100401ull;        // col-0 bit of 5 rows
        const uint64_t NC0 = M50 & ~C0;
        const uint64_t NC9 = M50 & ~(C0 << 9);
        uint64_t clo = 0, chi = 0;
        if (idx0 < 50) clo = 1ull << idx0; else chi = 1ull << (idx0 - 50);
#pragma unroll 1
        for (int it = 0; it < GH + GW; ++it) {        // cap 20 = reference
            const uint64_t hlo = clo | ((clo << 1) & NC0) | ((clo >> 1) & NC9);
            const uint64_t hhi = chi | ((chi << 1) & NC0) | ((chi >> 1) & NC9);
            uint64_t nlo = (hlo | (hlo << 10) | (hlo >> 10) | ((hhi & 0x3FFull) << 40)) & mlo;
            uint64_t nhi = (hhi | (hhi << 10) | (hhi >> 10) | (hlo >> 40)) & mhi;
            nlo |= clo; nhi |= chi;
            if (nlo == clo && nhi == chi) break;      // exit only at fixpoint
            clo = nlo; chi = nhi;
        }
        const int K = __popcll(clo) + __popcll(chi);

        // ---- S_T over own cells (values still in registers) ----
        // in_cl[y][x] = cluster bit (x*10+y); y = 5h+i -> pre-shift by 5h
        const uint64_t wlo = clo >> (5 * h);
        const uint64_t whi = chi >> (5 * h);
        float st_h = 0.f;
#pragma unroll
        for (int i = 0; i < 5; ++i) {
            const float* v = vv + 10 * i;
#pragma unroll
            for (int x = 0; x < 10; ++x) {
                const uint64_t w = (x < 5) ? wlo : whi;    // compile-time sel
                const uint32_t bit = (uint32_t)((w >> ((x % 5) * 10 + i)) & 1ull);
                st_h = fmaf((float)bit, v[x], st_h);
            }
        }
        const float S_T = st_h + __shfl_xor(st_h, 1);

        // ---- argmin (own 5 rows, then pair merge; first-flat-index ties) ----
        int bestd = 1000, bidx = 0;
        const uint64_t cw = h ? chi : clo;
#pragma unroll
        for (int i = 0; i < 5; ++i) {
            const int y = 5 * h + i;
            const uint32_t rb = (uint32_t)((cw >> (10 * i)) & 0x3FFull);
            const uint32_t left  = rb & ((2u << p1x) - 1);
            const uint32_t right = rb >> p1x;
            const int dl = left  ? (p1x - (31 - __builtin_clz(left))) : 1000;
            const int dr = right ? __builtin_ctz(right) : 1000;
            int dx, xx;
            if (dl <= dr) { dx = dl; xx = p1x - dl; }      // tie -> smaller col
            else          { dx = dr; xx = p1x + dr; }
            const int d = abs(y - p1y) + dx;
            if (rb && d < bestd) { bestd = d; bidx = y * GW + xx; }
        }
        {   // pair merge; tie -> smaller flat index
            const int od = __shfl_xor(bestd, 1);
            const int oi = __shfl_xor(bidx, 1);
            if (od < bestd || (od == bestd && oi < bidx)) { bestd = od; bidx = oi; }
        }

        // ---- epilogue (replicated; only h==0 contributes) ----
        const bool better = bestd < base0;
        const int ny = better ? bidx / 10 : p0y;
        const int nx = better ? bidx % 10 : p0x;
        const int gap = min(base0, bestd);

        int by = ny, bx = nx, bg = gap;
        const int oy = p1y - ny, ox = p1x - nx;
        auto upd = [&](bool cond, int cy, int cx) {
            const int d = abs(cy - p1y) + abs(cx - p1x);
            if (cond && (d < bg)) { by = cy; bx = cx; bg = d; }
        };
        upd(ox < 0,                     ny,     nx - 1);
        upd((ox < 0) && (ny != 0),      ny - 1, nx - 1);
        upd((ox < 0) && (ny != GH - 1), ny + 1, nx - 1);
        upd(ox > 0,                     ny,     nx + 1);
        upd((ox > 0) && (ny != 0),      ny - 1, nx + 1);
        upd((ox > 0) && (ny != GH - 1), ny + 1, nx + 1);
        upd(oy < 0,                     ny - 1, nx);
        upd(oy > 0,                     ny + 1, nx);
        const int ncy = min(max(by, 0), GH - 1);
        const int ncx = min(max(bx, 0), GW - 1);
        const float rn = sp[ncy * GW + ncx];  // L1/L2-hot gather

        const float csf = (float)K;
        const float nboxf = (float)((dy0 + 1) * (dx0 + 1));
        const float loss_start = (2.f - (rs + re)) * 1000.f;
        const float lon = 5.f * csf + 15.f * sum_all - 20.f * S_T;
        const float single_cell = 0.5f * sc + 20.f * (nboxf - boxSum);
        const float cpen = 12.f * csf * S_T;
        const float gap_pen = (float)gap * 300.f * (1.f - rn);
        loss = loss_start + lon + single_cell + cpen + gap_pen;
        if (h != 0) loss = 0.f;                   // one contribution per sample
    }

    // ---- block reduction: wave shuffle -> LDS -> one atomic per block ----
#pragma unroll
    for (int off = 32; off > 0; off >>= 1)
        loss += __shfl_down(loss, off);
    if (lane == 0) wsum[wid] = loss;
    __syncthreads();
    if (tix == 0)
        atomicAdd(out, wsum[0] + wsum[1] + wsum[2] + wsum[3]);
}

extern "C" void kernel_launch(void* const* d_in, const int* in_sizes, int n_in,
                              void* d_out, int out_size, void* d_ws, size_t ws_size,
                              hipStream_t stream)
{
    const float* result = (const float*)d_in[0];
    const int* points   = (const int*)d_in[1];
    float* out = (float*)d_out;
    const int B = in_sizes[0] / 100;
    hipMemsetAsync(out, 0, sizeof(float), stream);   // harness poisons d_out
    const int block = 256;                            // 128 samples per block
    const int grid = (2 * B + block - 1) / block;
    custom_loss_kernel<<<grid, block, 0, stream>>>(result, points, out, B);
}

// Round 10
// 181.165 us; speedup vs baseline: 1.0725x; 1.0725x over previous
//
#include <hip/hip_runtime.h>
#include <cstdint>

#define GH 10
#define GW 10

// Round 15: resubmission of r14 (round-9 bench died to an infra flake --
// "container failed twice" with no counters; the kernel has no risky
// constructs: plain HIP, same family as r2/r8 which ran fine).
// Theory under test (unchanged): r8 proved the load path was NOT r2's
// bottleneck (halving line-touches regressed 81us); the recurring failure
// across r1/r3/r8 is vv[50]'s live range -> AGPR parking (VGPR 52-64,
// zero scratch, ~150 hidden v_accvgpr moves/thread). This version never
// materializes the board:
//   1) stream 25xfloat2 -> mask bits only (2 floats live at a time)
//   2) flood fill (masks only)
//   3) re-stream same 25xfloat2 (L1/L2-hot, 12.8KB/wave working set)
//      -> pass-1 sums AND S_T fused per row (one row live)
// All FP chains keep r2's exact op order (same fma order, same bit
// values) -> absmax 0. Falsifiable: VGPR_Count should drop to ~48-56;
// if it stays >=64, the AGPR theory is wrong.
__global__ __launch_bounds__(256, 4) void custom_loss_kernel(
    const float* __restrict__ result,
    const int* __restrict__ points,
    float* __restrict__ out,
    int B)
{
    __shared__ float wsum[4];
    const int tix = threadIdx.x;
    const int lane = tix & 63;
    const int wid = tix >> 6;

    const int s_local = tix >> 1;             // sample within block (0..127)
    const int h = tix & 1;                    // half: rows 5h..5h+4
    const int s = blockIdx.x * 128 + s_local;

    float loss = 0.f;
    if (s < B) {
        const int4 p = ((const int4*)points)[s];
        const int p0y = p.x, p0x = p.y, p1y = p.z, p1x = p.w;
        const int dy0 = abs(p0y - p1y), dx0 = abs(p0x - p1x);
        const int base0 = dy0 + dx0;
        const int idx0 = p0y * GW + p0x;
        const int idx1 = p1y * GW + p1x;

        const float* __restrict__ sp = result + (size_t)s * 100;
        const float2* __restrict__ rp2 = (const float2*)(sp + h * 50);
        const float rs = sp[idx0];            // L1-hot gathers
        const float re = sp[idx1];

        // ---- stream 1: mask bits only (no board array kept) ----
        // bit layout identical to r2: bit = i*10 + x within own 50-bit word
        uint64_t mword = 0;
#pragma unroll
        for (int i = 0; i < 5; ++i) {
            uint32_t rm = 0u;
#pragma unroll
            for (int j2 = 0; j2 < 5; ++j2) {
                const float2 t = rp2[i * 5 + j2];
                // jnp.round half-to-even: for v in [0,1), round==1 <=> v>0.5
                rm |= (t.x > 0.5f) ? (1u << (2 * j2)) : 0u;
                rm |= (t.y > 0.5f) ? (1u << (2 * j2 + 1)) : 0u;
            }
            mword |= (uint64_t)rm << (10 * i);
        }
        const uint64_t mo = (uint64_t)__shfl_xor((unsigned long long)mword, 1);
        const uint64_t mlo = h ? mo : mword;
        const uint64_t mhi = h ? mword : mo;

        // ---- flood fill: full board per lane (lockstep pair, no sync) ----
        const uint64_t M50 = (1ull << 50) - 1;
        const uint64_t C0  = 0x10040100401ull;        // col-0 bit of 5 rows
        const uint64_t NC0 = M50 & ~C0;
        const uint64_t NC9 = M50 & ~(C0 << 9);
        uint64_t clo = 0, chi = 0;
        if (idx0 < 50) clo = 1ull << idx0; else chi = 1ull << (idx0 - 50);
#pragma unroll 1
        for (int it = 0; it < GH + GW; ++it) {        // cap 20 = reference
            const uint64_t hlo = clo | ((clo << 1) & NC0) | ((clo >> 1) & NC9);
            const uint64_t hhi = chi | ((chi << 1) & NC0) | ((chi >> 1) & NC9);
            uint64_t nlo = (hlo | (hlo << 10) | (hlo >> 10) | ((hhi & 0x3FFull) << 40)) & mlo;
            uint64_t nhi = (hhi | (hhi << 10) | (hhi >> 10) | (hlo >> 40)) & mhi;
            nlo |= clo; nhi |= chi;
            if (nlo == clo && nhi == chi) break;      // exit only at fixpoint
            clo = nlo; chi = nhi;
        }
        const int K = __popcll(clo) + __popcll(chi);

        // cluster bits for own rows: in_cl[y][x] = bit (x*10+y), y = 5h+i
        // fld[x] = 5 bits (i=0..4) of column x -> same bit values as r2
        const uint64_t wlo = clo >> (5 * h);
        const uint64_t whi = chi >> (5 * h);
        uint32_t fld[10];
#pragma unroll
        for (int x = 0; x < 10; ++x) {
            const uint64_t w = (x < 5) ? wlo : whi;        // compile-time sel
            fld[x] = (uint32_t)((w >> ((x % 5) * 10)) & 0x1Full);
        }

        float adxf[10], inboxf[10];           // compile-time indexed -> regs
#pragma unroll
        for (int x = 0; x < 10; ++x) {
            const int a = abs(x - p0x) + abs(x - p1x) - dx0;
            adxf[x] = (float)a;
            inboxf[x] = (a == 0) ? 1.f : 0.f;
        }

        // ---- stream 2: pass-1 sums AND S_T fused, one row live at a time ----
        // each chain keeps r2's exact accumulation order -> bit-identical
        float sum_h = 0.f, sc_h = 0.f, box_h = 0.f, st_h = 0.f;
#pragma unroll
        for (int i = 0; i < 5; ++i) {
            const int y = 5 * h + i;
            float v[10];
#pragma unroll
            for (int j2 = 0; j2 < 5; ++j2) {
                const float2 t = rp2[i * 5 + j2];      // L1/L2-hot re-read
                v[2 * j2] = t.x; v[2 * j2 + 1] = t.y;
            }
            const float rowacc = ((v[0]+v[1])+(v[2]+v[3])) +
                                 ((v[4]+v[5])+(v[6]+v[7])) + (v[8]+v[9]);
            sum_h += rowacc;
            const int ay = abs(y - p0y) + abs(y - p1y) - dy0;
            sc_h = fmaf((float)ay, rowacc, sc_h);
            float boxrow = 0.f;
#pragma unroll
            for (int x = 0; x < 10; ++x) {
                sc_h = fmaf(adxf[x], v[x], sc_h);
                boxrow = fmaf(inboxf[x], v[x], boxrow);
                st_h = fmaf((float)((fld[x] >> i) & 1u), v[x], st_h);
            }
            box_h += (ay == 0) ? boxrow : 0.f;
        }
        const float sum_all = sum_h + __shfl_xor(sum_h, 1);
        const float sc      = sc_h  + __shfl_xor(sc_h, 1);
        const float boxSum  = box_h + __shfl_xor(box_h, 1);
        const float S_T     = st_h  + __shfl_xor(st_h, 1);

        // ---- argmin (own 5 rows, then pair merge; first-flat-index ties) ----
        int bestd = 1000, bidx = 0;
        const uint64_t cw = h ? chi : clo;
#pragma unroll
        for (int i = 0; i < 5; ++i) {
            const int y = 5 * h + i;
            const uint32_t rb = (uint32_t)((cw >> (10 * i)) & 0x3FFull);
            const uint32_t left  = rb & ((2u << p1x) - 1);
            const uint32_t right = rb >> p1x;
            const int dl = left  ? (p1x - (31 - __builtin_clz(left))) : 1000;
            const int dr = right ? __builtin_ctz(right) : 1000;
            int dx, xx;
            if (dl <= dr) { dx = dl; xx = p1x - dl; }      // tie -> smaller col
            else          { dx = dr; xx = p1x + dr; }
            const int d = abs(y - p1y) + dx;
            if (rb && d < bestd) { bestd = d; bidx = y * GW + xx; }
        }
        {   // pair merge; tie -> smaller flat index
            const int od = __shfl_xor(bestd, 1);
            const int oi = __shfl_xor(bidx, 1);
            if (od < bestd || (od == bestd && oi < bidx)) { bestd = od; bidx = oi; }
        }

        // ---- epilogue (replicated; only h==0 contributes) ----
        const bool better = bestd < base0;
        const int ny = better ? bidx / 10 : p0y;
        const int nx = better ? bidx % 10 : p0x;
        const int gap = min(base0, bestd);

        int by = ny, bx = nx, bg = gap;
        const int oy = p1y - ny, ox = p1x - nx;
        auto upd = [&](bool cond, int cy, int cx) {
            const int d = abs(cy - p1y) + abs(cx - p1x);
            if (cond && (d < bg)) { by = cy; bx = cx; bg = d; }
        };
        upd(ox < 0,                     ny,     nx - 1);
        upd((ox < 0) && (ny != 0),      ny - 1, nx - 1);
        upd((ox < 0) && (ny != GH - 1), ny + 1, nx - 1);
        upd(ox > 0,                     ny,     nx + 1);
        upd((ox > 0) && (ny != 0),      ny - 1, nx + 1);
        upd((ox > 0) && (ny != GH - 1), ny + 1, nx + 1);
        upd(oy < 0,                     ny - 1, nx);
        upd(oy > 0,                     ny + 1, nx);
        const int ncy = min(max(by, 0), GH - 1);
        const int ncx = min(max(bx, 0), GW - 1);
        const float rn = sp[ncy * GW + ncx];  // L1/L2-hot gather

        const float csf = (float)K;
        const float nboxf = (float)((dy0 + 1) * (dx0 + 1));
        const float loss_start = (2.f - (rs + re)) * 1000.f;
        const float lon = 5.f * csf + 15.f * sum_all - 20.f * S_T;
        const float single_cell = 0.5f * sc + 20.f * (nboxf - boxSum);
        const float cpen = 12.f * csf * S_T;
        const float gap_pen = (float)gap * 300.f * (1.f - rn);
        loss = loss_start + lon + single_cell + cpen + gap_pen;
        if (h != 0) loss = 0.f;                   // one contribution per sample
    }

    // ---- block reduction: wave shuffle -> LDS -> one atomic per block ----
#pragma unroll
    for (int off = 32; off > 0; off >>= 1)
        loss += __shfl_down(loss, off);
    if (lane == 0) wsum[wid] = loss;
    __syncthreads();
    if (tix == 0)
        atomicAdd(out, wsum[0] + wsum[1] + wsum[2] + wsum[3]);
}

extern "C" void kernel_launch(void* const* d_in, const int* in_sizes, int n_in,
                              void* d_out, int out_size, void* d_ws, size_t ws_size,
                              hipStream_t stream)
{
    const float* result = (const float*)d_in[0];
    const int* points   = (const int*)d_in[1];
    float* out = (float*)d_out;
    const int B = in_sizes[0] / 100;
    hipMemsetAsync(out, 0, sizeof(float), stream);   // harness poisons d_out
    const int block = 256;                            // 128 samples per block
    const int grid = (2 * B + block - 1) / block;
    custom_loss_kernel<<<grid, block, 0, stream>>>(result, points, out, B);
}

// Round 11
// 164.347 us; speedup vs baseline: 1.1823x; 1.1023x over previous
//
#include <hip/hip_runtime.h>
#include <cstdint>

#define GH 10
#define GW 10

// Round 16: r2 base (single stream, board live in registers -- best measured,
// harness 164.4) + pair-split flood fill.
// Post-mortems: r8 (wide loads) and r10 (no-board re-stream) both regressed
// r2 -> neither load width nor board liveness was the binding constraint.
// r10's FETCH doubled to 109MB: "L1-hot re-stream" was wrong (13 waves/CU x
// 12.8KB >> 32KB L1). Remaining duplication: both lanes of a sample pair run
// the IDENTICAL flood fill (~60% of VALU, longest serial chain). Fix: lane h
// owns only its 50-bit word (== its mword; mask exchange deleted). Per iter:
// horizontal expand own word, exchange expanded word via one shfl_xor (DS
// pipe, idle), vertical + cross (h ? hp>>40 : hp<<40) + mask. Synchronous
// trajectory bit-identical to r2's (same per-iter lo/hi states, same 20-cap;
// fixpoint absorbing -> wave-wide __all convergence gives identical words).
// One final 64-bit exchange rebuilds clo/chi; everything downstream is r2
// verbatim -> absmax 0.
__global__ __launch_bounds__(256, 4) void custom_loss_kernel(
    const float* __restrict__ result,
    const int* __restrict__ points,
    float* __restrict__ out,
    int B)
{
    __shared__ float wsum[4];
    const int tix = threadIdx.x;
    const int lane = tix & 63;
    const int wid = tix >> 6;

    const int s_local = tix >> 1;             // sample within block (0..127)
    const int h = tix & 1;                    // half: rows 5h..5h+4
    const int s = blockIdx.x * 128 + s_local;

    float loss = 0.f;
    if (s < B) {
        const int4 p = ((const int4*)points)[s];
        const int p0y = p.x, p0x = p.y, p1y = p.z, p1x = p.w;
        const int dy0 = abs(p0y - p1y), dx0 = abs(p0x - p1x);
        const int base0 = dy0 + dx0;
        const int idx0 = p0y * GW + p0x;
        const int idx1 = p1y * GW + p1x;

        // ---- own 5 rows (50 floats) straight from global into registers ----
        const float* __restrict__ sp = result + (size_t)s * 100;
        const float2* __restrict__ rp2 = (const float2*)(sp + h * 50);
        float vv[50];
#pragma unroll
        for (int i = 0; i < 25; ++i) {
            const float2 t = rp2[i];
            vv[2 * i] = t.x; vv[2 * i + 1] = t.y;
        }
        const float rs = sp[idx0];            // L1-hot: lines just fetched
        const float re = sp[idx1];

        float adxf[10], inboxf[10];           // compile-time indexed -> regs
#pragma unroll
        for (int x = 0; x < 10; ++x) {
            const int a = abs(x - p0x) + abs(x - p1x) - dx0;
            adxf[x] = (float)a;
            inboxf[x] = (a == 0) ? 1.f : 0.f;
        }

        // ---- pass 1 over own rows ----
        float sum_h = 0.f, sc_h = 0.f, box_h = 0.f;
        uint64_t mword = 0;                   // own 50-bit mask, bit = i*10+x
#pragma unroll
        for (int i = 0; i < 5; ++i) {
            const int y = 5 * h + i;
            const float* v = vv + 10 * i;
            const float rowacc = ((v[0]+v[1])+(v[2]+v[3])) +
                                 ((v[4]+v[5])+(v[6]+v[7])) + (v[8]+v[9]);
            sum_h += rowacc;
            const int ay = abs(y - p0y) + abs(y - p1y) - dy0;
            sc_h = fmaf((float)ay, rowacc, sc_h);
            float boxrow = 0.f;
            uint32_t rm = 0u;
#pragma unroll
            for (int x = 0; x < 10; ++x) {
                sc_h = fmaf(adxf[x], v[x], sc_h);
                boxrow = fmaf(inboxf[x], v[x], boxrow);
                // jnp.round half-to-even: for v in [0,1), round==1 <=> v>0.5
                rm |= (v[x] > 0.5f) ? (1u << x) : 0u;
            }
            box_h += (ay == 0) ? boxrow : 0.f;
            mword |= (uint64_t)rm << (10 * i);
        }
        const float sum_all = sum_h + __shfl_xor(sum_h, 1);
        const float sc      = sc_h  + __shfl_xor(sc_h, 1);
        const float boxSum  = box_h + __shfl_xor(box_h, 1);

        // ---- flood fill: pair-split, one 50-bit word per lane ----
        // lane h owns word h (lo = rows 0-4, hi = rows 5-9); msk == mword.
        const uint64_t M50 = (1ull << 50) - 1;
        const uint64_t C0  = 0x10040100401ull;        // col-0 bit of 5 rows
        const uint64_t NC0 = M50 & ~C0;
        const uint64_t NC9 = M50 & ~(C0 << 9);
        const uint64_t msk = mword;
        uint64_t c = 0;
        if (h == 0) { if (idx0 < 50)  c = 1ull << idx0; }
        else        { if (idx0 >= 50) c = 1ull << (idx0 - 50); }
#pragma unroll 1
        for (int it = 0; it < GH + GW; ++it) {        // cap 20 = reference
            const uint64_t hx = c | ((c << 1) & NC0) | ((c >> 1) & NC9);
            const uint64_t hp = (uint64_t)__shfl_xor((unsigned long long)hx, 1);
            const uint64_t cross = h ? (hp >> 40) : (hp << 40);
            uint64_t n = (hx | (hx << 10) | (hx >> 10) | cross) & msk;
            n |= c;
            const int same = (n == c) ? 1 : 0;
            c = n;
            if (__all(same)) break;           // fixpoint absorbing: converged
        }                                     // pairs idle harmlessly
        const uint64_t cOth = (uint64_t)__shfl_xor((unsigned long long)c, 1);
        const uint64_t clo = h ? cOth : c;
        const uint64_t chi = h ? c : cOth;
        const int K = __popcll(clo) + __popcll(chi);

        // ---- S_T over own cells (values still in registers) ----
        // in_cl[y][x] = cluster bit (x*10+y); y = 5h+i -> pre-shift by 5h
        const uint64_t wlo = clo >> (5 * h);
        const uint64_t whi = chi >> (5 * h);
        float st_h = 0.f;
#pragma unroll
        for (int i = 0; i < 5; ++i) {
            const float* v = vv + 10 * i;
#pragma unroll
            for (int x = 0; x < 10; ++x) {
                const uint64_t w = (x < 5) ? wlo : whi;    // compile-time sel
                const uint32_t bit = (uint32_t)((w >> ((x % 5) * 10 + i)) & 1ull);
                st_h = fmaf((float)bit, v[x], st_h);
            }
        }
        const float S_T = st_h + __shfl_xor(st_h, 1);

        // ---- argmin (own 5 rows, then pair merge; first-flat-index ties) ----
        int bestd = 1000, bidx = 0;
        const uint64_t cw = h ? chi : clo;    // == own word c
#pragma unroll
        for (int i = 0; i < 5; ++i) {
            const int y = 5 * h + i;
            const uint32_t rb = (uint32_t)((cw >> (10 * i)) & 0x3FFull);
            const uint32_t left  = rb & ((2u << p1x) - 1);
            const uint32_t right = rb >> p1x;
            const int dl = left  ? (p1x - (31 - __builtin_clz(left))) : 1000;
            const int dr = right ? __builtin_ctz(right) : 1000;
            int dx, xx;
            if (dl <= dr) { dx = dl; xx = p1x - dl; }      // tie -> smaller col
            else          { dx = dr; xx = p1x + dr; }
            const int d = abs(y - p1y) + dx;
            if (rb && d < bestd) { bestd = d; bidx = y * GW + xx; }
        }
        {   // pair merge; tie -> smaller flat index
            const int od = __shfl_xor(bestd, 1);
            const int oi = __shfl_xor(bidx, 1);
            if (od < bestd || (od == bestd && oi < bidx)) { bestd = od; bidx = oi; }
        }

        // ---- epilogue (replicated; only h==0 contributes) ----
        const bool better = bestd < base0;
        const int ny = better ? bidx / 10 : p0y;
        const int nx = better ? bidx % 10 : p0x;
        const int gap = min(base0, bestd);

        int by = ny, bx = nx, bg = gap;
        const int oy = p1y - ny, ox = p1x - nx;
        auto upd = [&](bool cond, int cy, int cx) {
            const int d = abs(cy - p1y) + abs(cx - p1x);
            if (cond && (d < bg)) { by = cy; bx = cx; bg = d; }
        };
        upd(ox < 0,                     ny,     nx - 1);
        upd((ox < 0) && (ny != 0),      ny - 1, nx - 1);
        upd((ox < 0) && (ny != GH - 1), ny + 1, nx - 1);
        upd(ox > 0,                     ny,     nx + 1);
        upd((ox > 0) && (ny != 0),      ny - 1, nx + 1);
        upd((ox > 0) && (ny != GH - 1), ny + 1, nx + 1);
        upd(oy < 0,                     ny - 1, nx);
        upd(oy > 0,                     ny + 1, nx);
        const int ncy = min(max(by, 0), GH - 1);
        const int ncx = min(max(bx, 0), GW - 1);
        const float rn = sp[ncy * GW + ncx];  // L1/L2-hot gather

        const float csf = (float)K;
        const float nboxf = (float)((dy0 + 1) * (dx0 + 1));
        const float loss_start = (2.f - (rs + re)) * 1000.f;
        const float lon = 5.f * csf + 15.f * sum_all - 20.f * S_T;
        const float single_cell = 0.5f * sc + 20.f * (nboxf - boxSum);
        const float cpen = 12.f * csf * S_T;
        const float gap_pen = (float)gap * 300.f * (1.f - rn);
        loss = loss_start + lon + single_cell + cpen + gap_pen;
        if (h != 0) loss = 0.f;                   // one contribution per sample
    }

    // ---- block reduction: wave shuffle -> LDS -> one atomic per block ----
#pragma unroll
    for (int off = 32; off > 0; off >>= 1)
        loss += __shfl_down(loss, off);
    if (lane == 0) wsum[wid] = loss;
    __syncthreads();
    if (tix == 0)
        atomicAdd(out, wsum[0] + wsum[1] + wsum[2] + wsum[3]);
}

extern "C" void kernel_launch(void* const* d_in, const int* in_sizes, int n_in,
                              void* d_out, int out_size, void* d_ws, size_t ws_size,
                              hipStream_t stream)
{
    const float* result = (const float*)d_in[0];
    const int* points   = (const int*)d_in[1];
    float* out = (float*)d_out;
    const int B = in_sizes[0] / 100;
    hipMemsetAsync(out, 0, sizeof(float), stream);   // harness poisons d_out
    const int block = 256;                            // 128 samples per block
    const int grid = (2 * B + block - 1) / block;
    custom_loss_kernel<<<grid, block, 0, stream>>>(result, points, out, B);
}